// Round 1
// baseline (1096.698 us; speedup 1.0000x reference)
//
#include <hip/hip_runtime.h>
#include <hip/hip_bf16.h>

#define N_SRC 10000
#define N_DST 40000
#define NE    1280000
#define IN_DIM 128
#define O_DIM  300
#define D      64
#define FEAT   64

typedef __bf16 bf16x8 __attribute__((ext_vector_type(8)));
typedef float  f32x4  __attribute__((ext_vector_type(4)));

// order-preserving float->uint key for atomicMax-based float max
__device__ __forceinline__ unsigned fkey(float x){
    unsigned u = __float_as_uint(x);
    return (u & 0x80000000u) ? ~u : (u | 0x80000000u);
}
__device__ __forceinline__ float funkey(unsigned k){
    unsigned u = (k & 0x80000000u) ? (k ^ 0x80000000u) : ~k;
    return __uint_as_float(u);
}

// ---------------- K1: z_src = h @ W_fc  [10000x128]@[128x64] ----------------
__global__ __launch_bounds__(256) void k_zsrc(const float* __restrict__ h,
                                              const float* __restrict__ Wfc,
                                              float* __restrict__ z){
    __shared__ float w[IN_DIM * D]; // 32 KB
    for (int i = threadIdx.x; i < IN_DIM * D; i += blockDim.x) w[i] = Wfc[i];
    __syncthreads();
    int lane = threadIdx.x & 63;
    int wid  = blockIdx.x * 4 + (threadIdx.x >> 6);
    int nw   = gridDim.x * 4;
    for (int row = wid; row < N_SRC; row += nw){
        const f32x4* hp = (const f32x4*)(h + (size_t)row * IN_DIM);
        float acc = 0.f;
        #pragma unroll 4
        for (int k4 = 0; k4 < IN_DIM / 4; ++k4){
            f32x4 hv = hp[k4];
            int k = k4 * 4;
            acc += hv[0] * w[(k + 0) * D + lane];
            acc += hv[1] * w[(k + 1) * D + lane];
            acc += hv[2] * w[(k + 2) * D + lane];
            acc += hv[3] * w[(k + 3) * D + lane];
        }
        z[(size_t)row * D + lane] = acc;
    }
}

// ---------------- K2: z_dst = o @ W_fc1  [40000x300]@[300x64] ---------------
__global__ __launch_bounds__(256) void k_zdst(const float* __restrict__ o,
                                              const float* __restrict__ Wfc1,
                                              float* __restrict__ z){
    extern __shared__ float w[]; // 300*64*4 = 76.8 KB
    for (int i = threadIdx.x; i < O_DIM * D; i += blockDim.x) w[i] = Wfc1[i];
    __syncthreads();
    int lane = threadIdx.x & 63;
    int wid  = blockIdx.x * 4 + (threadIdx.x >> 6);
    int nw   = gridDim.x * 4;
    for (int row = wid; row < N_DST; row += nw){
        const f32x4* op = (const f32x4*)(o + (size_t)row * O_DIM);
        float acc = 0.f;
        #pragma unroll 5
        for (int k4 = 0; k4 < O_DIM / 4; ++k4){
            f32x4 ov = op[k4];
            int k = k4 * 4;
            acc += ov[0] * w[(k + 0) * D + lane];
            acc += ov[1] * w[(k + 1) * D + lane];
            acc += ov[2] * w[(k + 2) * D + lane];
            acc += ov[3] * w[(k + 3) * D + lane];
        }
        z[(size_t)row * D + lane] = acc;
    }
}

// ---------------- K3: per-edge attention score + segment max ----------------
// One wave processes 16 edges. C = W_feat^T (dims, M) x tfidf^T (edges, N):
// MFMA 16x16x32_bf16, 4 M-tiles of 16 dims, K=64 in 2 halves.
// C/D layout: col(edge)=lane&15, row(dim)=mt*16 + (lane>>4)*4 + reg
// -> each lane holds 4 CONSECUTIVE dims of one edge per M-tile, so the
//    z_src/z_dst gathers are float4 loads and e-reduction is 2 shfl_xors.
__global__ __launch_bounds__(256) void k_edge(
        const float* __restrict__ tfidf,
        const int*   __restrict__ esrc, const int* __restrict__ edst,
        const float* __restrict__ zsrc, const float* __restrict__ zdst,
        const float* __restrict__ Wfeat, const float* __restrict__ bfeat,
        const float* __restrict__ Wattn,
        float* __restrict__ escore, unsigned* __restrict__ mkeys){
    int lane = threadIdx.x & 63;
    int lo = lane & 15, g = lane >> 4;

    // A-frags: A[m=dim][k] = W_feat[k][dim]; lane holds m=mt*16+lo, k=kh*32+g*8+j
    bf16x8 afr[4][2];
    #pragma unroll
    for (int mt = 0; mt < 4; ++mt){
        int m = mt * 16 + lo;
        #pragma unroll
        for (int kh = 0; kh < 2; ++kh){
            #pragma unroll
            for (int j = 0; j < 8; ++j){
                int k = kh * 32 + g * 8 + j;
                afr[mt][kh][j] = (__bf16)Wfeat[k * D + m];
            }
        }
    }
    // per-lane bias / attention weights for the 4 dims this lane owns per M-tile
    f32x4 bf4[4], wa4[4];
    #pragma unroll
    for (int mt = 0; mt < 4; ++mt){
        int db = mt * 16 + g * 4;
        bf4[mt] = *(const f32x4*)(bfeat + db);
        wa4[mt] = *(const f32x4*)(Wattn + db);
    }

    int wid = blockIdx.x * 4 + (threadIdx.x >> 6);
    int nw  = gridDim.x * 4;
    for (int tile = wid; tile < NE / 16; tile += nw){
        int e0  = tile * 16;
        int myE = e0 + lo;
        int s = esrc[myE], d = edst[myE];

        // B-frags: B[k][n=edge] = tfidf[edge][k]; lane holds n=lo, k=kh*32+g*8+j
        const float* trow = tfidf + (size_t)myE * FEAT;
        bf16x8 bfr[2];
        #pragma unroll
        for (int kh = 0; kh < 2; ++kh){
            f32x4 fa = *(const f32x4*)(trow + kh * 32 + g * 8);
            f32x4 fb = *(const f32x4*)(trow + kh * 32 + g * 8 + 4);
            #pragma unroll
            for (int j = 0; j < 4; ++j){
                bfr[kh][j]     = (__bf16)fa[j];
                bfr[kh][4 + j] = (__bf16)fb[j];
            }
        }

        float p = 0.f;
        #pragma unroll
        for (int mt = 0; mt < 4; ++mt){
            f32x4 acc = {0.f, 0.f, 0.f, 0.f};
            acc = __builtin_amdgcn_mfma_f32_16x16x32_bf16(afr[mt][0], bfr[0], acc, 0, 0, 0);
            acc = __builtin_amdgcn_mfma_f32_16x16x32_bf16(afr[mt][1], bfr[1], acc, 0, 0, 0);
            int db = mt * 16 + g * 4;
            f32x4 zs = *(const f32x4*)(zsrc + (size_t)s * D + db);
            f32x4 zd = *(const f32x4*)(zdst + (size_t)d * D + db);
            #pragma unroll
            for (int r = 0; r < 4; ++r){
                float z2 = acc[r] + zs[r] + zd[r] + bf4[mt][r];
                float z3 = z2 > 0.f ? z2 : 0.01f * z2;   // leaky_relu(0.01)
                p += z3 * wa4[mt][r];
            }
        }
        // sum over dims: lanes {e, e+16, e+32, e+48} hold partials of edge e
        p += __shfl_xor(p, 16);
        p += __shfl_xor(p, 32);
        if (lane < 16){
            escore[e0 + lane] = p;
            atomicMax(&mkeys[d], fkey(p));
        }
    }
}

// ---------------- K4: e_exp = exp(e - m[dst]); denom[dst] += e_exp ----------
__global__ __launch_bounds__(256) void k_expsum(const int* __restrict__ edst,
                                                const unsigned* __restrict__ mkeys,
                                                float* __restrict__ escore,
                                                float* __restrict__ denom){
    int i = blockIdx.x * blockDim.x + threadIdx.x;
    if (i >= NE) return;
    int d = edst[i];
    float m  = funkey(mkeys[d]);
    float ex = __expf(escore[i] - m);
    escore[i] = ex;           // in-place: escore becomes e_exp
    atomicAdd(&denom[d], ex);
}

// ---------------- K5: out[dst] += alpha * z_src[src] ------------------------
__global__ __launch_bounds__(256) void k_scatter(const int* __restrict__ esrc,
                                                 const int* __restrict__ edst,
                                                 const float* __restrict__ eexp,
                                                 const float* __restrict__ denom,
                                                 const float* __restrict__ zsrc,
                                                 float* __restrict__ out){
    int lane = threadIdx.x & 63;
    int wid  = blockIdx.x * 4 + (threadIdx.x >> 6);
    int nw   = gridDim.x * 4;
    for (int e = wid; e < NE; e += nw){
        int s = esrc[e], d = edst[e];
        float alpha = eexp[e] / fmaxf(denom[d], 1e-9f);
        atomicAdd(&out[(size_t)d * D + lane], alpha * zsrc[(size_t)s * D + lane]);
    }
}

extern "C" void kernel_launch(void* const* d_in, const int* in_sizes, int n_in,
                              void* d_out, int out_size, void* d_ws, size_t ws_size,
                              hipStream_t stream) {
    const float* h     = (const float*)d_in[0];
    const float* o     = (const float*)d_in[1];
    const float* tfidf = (const float*)d_in[2];
    const float* Wfc   = (const float*)d_in[3];
    const float* Wfc1  = (const float*)d_in[4];
    const float* Wfeat = (const float*)d_in[5];
    const float* bfeat = (const float*)d_in[6];
    const float* Wattn = (const float*)d_in[7];
    const int*   esrc  = (const int*)d_in[8];
    const int*   edst  = (const int*)d_in[9];
    float* out = (float*)d_out;

    // workspace layout (floats): zsrc[640000] zdst[2560000] escore[1280000]
    //                            mkeys[40000] denom[40000]  => 18.24 MB
    float*    ws     = (float*)d_ws;
    float*    zsrc   = ws;
    float*    zdst   = ws + 640000;
    float*    escore = ws + 640000 + 2560000;
    unsigned* mkeys  = (unsigned*)(ws + 4480000);
    float*    denom  = ws + 4520000;

    // mkeys=0 is the minimum flip-key (~ -NaN), denom=0; they are adjacent
    hipMemsetAsync(mkeys, 0, 2 * 40000 * sizeof(float), stream);
    hipMemsetAsync(out, 0, (size_t)out_size * sizeof(float), stream);

    k_zsrc<<<256, 256, 0, stream>>>(h, Wfc, zsrc);
    k_zdst<<<512, 256, O_DIM * D * sizeof(float), stream>>>(o, Wfc1, zdst);
    k_edge<<<2048, 256, 0, stream>>>(tfidf, esrc, edst, zsrc, zdst,
                                     Wfeat, bfeat, Wattn, escore, mkeys);
    k_expsum<<<NE / 256, 256, 0, stream>>>(edst, mkeys, escore, denom);
    k_scatter<<<8192, 256, 0, stream>>>(esrc, edst, escore, denom, zsrc, out);
}

// Round 2
// 1024.689 us; speedup vs baseline: 1.0703x; 1.0703x over previous
//
#include <hip/hip_runtime.h>
#include <hip/hip_bf16.h>

#define N_SRC 10000
#define N_DST 40000
#define NE    1280000
#define IN_DIM 128
#define O_DIM  300
#define D      64
#define FEAT   64

typedef __bf16 bf16x8 __attribute__((ext_vector_type(8)));
typedef float  f32x4  __attribute__((ext_vector_type(4)));

// ---------------- K1: z_src = h @ W_fc  [10000x128]@[128x64] ----------------
__global__ __launch_bounds__(256) void k_zsrc(const float* __restrict__ h,
                                              const float* __restrict__ Wfc,
                                              float* __restrict__ z){
    __shared__ float w[IN_DIM * D]; // 32 KB
    for (int i = threadIdx.x; i < IN_DIM * D; i += blockDim.x) w[i] = Wfc[i];
    __syncthreads();
    int lane = threadIdx.x & 63;
    int wid  = blockIdx.x * 4 + (threadIdx.x >> 6);
    int nw   = gridDim.x * 4;
    for (int row = wid; row < N_SRC; row += nw){
        const f32x4* hp = (const f32x4*)(h + (size_t)row * IN_DIM);
        float acc = 0.f;
        #pragma unroll 4
        for (int k4 = 0; k4 < IN_DIM / 4; ++k4){
            f32x4 hv = hp[k4];
            int k = k4 * 4;
            acc += hv[0] * w[(k + 0) * D + lane];
            acc += hv[1] * w[(k + 1) * D + lane];
            acc += hv[2] * w[(k + 2) * D + lane];
            acc += hv[3] * w[(k + 3) * D + lane];
        }
        z[(size_t)row * D + lane] = acc;
    }
}

// ---------------- K2: z_dst = o @ W_fc1  [40000x300]@[300x64] ---------------
__global__ __launch_bounds__(256) void k_zdst(const float* __restrict__ o,
                                              const float* __restrict__ Wfc1,
                                              float* __restrict__ z){
    extern __shared__ float w[]; // 300*64*4 = 76.8 KB
    for (int i = threadIdx.x; i < O_DIM * D; i += blockDim.x) w[i] = Wfc1[i];
    __syncthreads();
    int lane = threadIdx.x & 63;
    int wid  = blockIdx.x * 4 + (threadIdx.x >> 6);
    int nw   = gridDim.x * 4;
    for (int row = wid; row < N_DST; row += nw){
        const f32x4* op = (const f32x4*)(o + (size_t)row * O_DIM);
        float acc = 0.f;
        #pragma unroll 5
        for (int k4 = 0; k4 < O_DIM / 4; ++k4){
            f32x4 ov = op[k4];
            int k = k4 * 4;
            acc += ov[0] * w[(k + 0) * D + lane];
            acc += ov[1] * w[(k + 1) * D + lane];
            acc += ov[2] * w[(k + 2) * D + lane];
            acc += ov[3] * w[(k + 3) * D + lane];
        }
        z[(size_t)row * D + lane] = acc;
    }
}

// ---------------- CSR build: histogram -> scan -> bucket --------------------
__global__ __launch_bounds__(256) void k_hist(const int* __restrict__ edst,
                                              int* __restrict__ cnt){
    int i = blockIdx.x * blockDim.x + threadIdx.x;
    if (i < NE) atomicAdd(&cnt[edst[i]], 1);
}

// single-block exclusive scan of cnt[40000] -> csr[40001] and cursor[40000]
__global__ __launch_bounds__(256) void k_scan(const int* __restrict__ cnt,
                                              int* __restrict__ csr,
                                              int* __restrict__ cursor){
    __shared__ int wsum[4];
    __shared__ int chunkbase;
    if (threadIdx.x == 0) chunkbase = 0;
    __syncthreads();
    int lane = threadIdx.x & 63, w = threadIdx.x >> 6;
    for (int chunk = 0; chunk < 40; ++chunk){
        int i0 = chunk * 1024 + threadIdx.x * 4;
        int c[4];
        #pragma unroll
        for (int r = 0; r < 4; ++r){
            int i = i0 + r;
            c[r] = (i < N_DST) ? cnt[i] : 0;
        }
        int tsum = c[0] + c[1] + c[2] + c[3];
        int v = tsum; // inclusive scan across 256 threads
        #pragma unroll
        for (int off = 1; off < 64; off <<= 1){
            int u = __shfl_up(v, off);
            if (lane >= off) v += u;
        }
        if (lane == 63) wsum[w] = v;
        __syncthreads();
        int woff = 0;
        for (int ww = 0; ww < w; ++ww) woff += wsum[ww];
        int run = chunkbase + woff + (v - tsum); // exclusive prefix for thread
        #pragma unroll
        for (int r = 0; r < 4; ++r){
            int i = i0 + r;
            if (i < N_DST){ csr[i] = run; cursor[i] = run; run += c[r]; }
        }
        __syncthreads();
        if (threadIdx.x == 0)
            chunkbase += wsum[0] + wsum[1] + wsum[2] + wsum[3];
        __syncthreads();
    }
    if (threadIdx.x == 0) csr[N_DST] = NE;
}

// for each edge: pos = cursor[dst]++; ssrc[pos]=src; epos[e]=pos
__global__ __launch_bounds__(256) void k_bucket(const int* __restrict__ esrc,
                                                const int* __restrict__ edst,
                                                int* __restrict__ cursor,
                                                int* __restrict__ ssrc,
                                                int* __restrict__ epos){
    int e = blockIdx.x * blockDim.x + threadIdx.x;
    if (e >= NE) return;
    int pos = atomicAdd(&cursor[edst[e]], 1);
    ssrc[pos] = esrc[e];
    epos[e]   = pos;
}

// ---------------- K3: per-edge attention score (written permuted) -----------
// One wave processes 16 edges. MFMA 16x16x32_bf16, C = W_feat^T x tfidf^T.
// C/D layout: col(edge)=lane&15, row(dim)=mt*16 + (lane>>4)*4 + reg
__global__ __launch_bounds__(256) void k_edge(
        const float* __restrict__ tfidf,
        const int*   __restrict__ esrc, const int* __restrict__ edst,
        const int*   __restrict__ epos,
        const float* __restrict__ zsrc, const float* __restrict__ zdst,
        const float* __restrict__ Wfeat, const float* __restrict__ bfeat,
        const float* __restrict__ Wattn,
        float* __restrict__ escore_p){
    int lane = threadIdx.x & 63;
    int lo = lane & 15, g = lane >> 4;

    // A-frags: A[m=dim][k] = W_feat[k][dim]; lane holds m=mt*16+lo, k=kh*32+g*8+j
    bf16x8 afr[4][2];
    #pragma unroll
    for (int mt = 0; mt < 4; ++mt){
        int m = mt * 16 + lo;
        #pragma unroll
        for (int kh = 0; kh < 2; ++kh){
            #pragma unroll
            for (int j = 0; j < 8; ++j){
                int k = kh * 32 + g * 8 + j;
                afr[mt][kh][j] = (__bf16)Wfeat[k * D + m];
            }
        }
    }
    f32x4 bf4[4], wa4[4];
    #pragma unroll
    for (int mt = 0; mt < 4; ++mt){
        int db = mt * 16 + g * 4;
        bf4[mt] = *(const f32x4*)(bfeat + db);
        wa4[mt] = *(const f32x4*)(Wattn + db);
    }

    int wid = blockIdx.x * 4 + (threadIdx.x >> 6);
    int nw  = gridDim.x * 4;
    for (int tile = wid; tile < NE / 16; tile += nw){
        int e0  = tile * 16;
        int myE = e0 + lo;
        int s = esrc[myE], d = edst[myE];

        // B-frags: B[k][n=edge]=tfidf[edge][k]; lane holds n=lo, k=kh*32+g*8+j
        const float* trow = tfidf + (size_t)myE * FEAT;
        bf16x8 bfr[2];
        #pragma unroll
        for (int kh = 0; kh < 2; ++kh){
            f32x4 fa = *(const f32x4*)(trow + kh * 32 + g * 8);
            f32x4 fb = *(const f32x4*)(trow + kh * 32 + g * 8 + 4);
            #pragma unroll
            for (int j = 0; j < 4; ++j){
                bfr[kh][j]     = (__bf16)fa[j];
                bfr[kh][4 + j] = (__bf16)fb[j];
            }
        }

        float p = 0.f;
        #pragma unroll
        for (int mt = 0; mt < 4; ++mt){
            f32x4 acc = {0.f, 0.f, 0.f, 0.f};
            acc = __builtin_amdgcn_mfma_f32_16x16x32_bf16(afr[mt][0], bfr[0], acc, 0, 0, 0);
            acc = __builtin_amdgcn_mfma_f32_16x16x32_bf16(afr[mt][1], bfr[1], acc, 0, 0, 0);
            int db = mt * 16 + g * 4;
            f32x4 zs = *(const f32x4*)(zsrc + (size_t)s * D + db);
            f32x4 zd = *(const f32x4*)(zdst + (size_t)d * D + db);
            #pragma unroll
            for (int r = 0; r < 4; ++r){
                float z2 = acc[r] + zs[r] + zd[r] + bf4[mt][r];
                float z3 = z2 > 0.f ? z2 : 0.01f * z2;   // leaky_relu(0.01)
                p += z3 * wa4[mt][r];
            }
        }
        p += __shfl_xor(p, 16);
        p += __shfl_xor(p, 32);
        if (lane < 16){
            escore_p[epos[e0 + lane]] = p;   // write in permuted (CSR) order
        }
    }
}

// ---------------- K4: fused segment softmax + weighted gather ---------------
// One wave per dst node. lane = dim in the accumulation phase.
__global__ __launch_bounds__(256) void k_post(const int* __restrict__ csr,
                                              const int* __restrict__ ssrc,
                                              const float* __restrict__ escore_p,
                                              const float* __restrict__ zsrc,
                                              float* __restrict__ out){
    int lane = threadIdx.x & 63;
    int d    = blockIdx.x * 4 + (threadIdx.x >> 6);
    if (d >= N_DST) return;
    int beg = csr[d], end = csr[d + 1];

    // pass A: segment max
    float m = -3.4e38f;
    for (int j = beg + lane; j < end; j += 64)
        m = fmaxf(m, escore_p[j]);
    #pragma unroll
    for (int off = 1; off < 64; off <<= 1)
        m = fmaxf(m, __shfl_xor(m, off));

    // pass B: exp-sum
    float ssum = 0.f;
    for (int j = beg + lane; j < end; j += 64)
        ssum += __expf(escore_p[j] - m);
    #pragma unroll
    for (int off = 1; off < 64; off <<= 1)
        ssum += __shfl_xor(ssum, off);
    float inv = 1.f / fmaxf(ssum, 1e-9f);

    // pass C: out[d][lane] = sum_e alpha_e * zsrc[src_e][lane]
    float acc = 0.f;
    for (int base = beg; base < end; base += 64){
        int n = end - base; if (n > 64) n = 64;
        int   sj = 0;
        float aj = 0.f;
        if (base + lane < end){
            sj = ssrc[base + lane];
            aj = __expf(escore_p[base + lane] - m) * inv;
        }
        for (int t = 0; t < n; ++t){
            int   s = __shfl(sj, t);
            float a = __shfl(aj, t);
            acc += a * zsrc[(size_t)s * D + lane];
        }
    }
    out[(size_t)d * D + lane] = acc;
}

extern "C" void kernel_launch(void* const* d_in, const int* in_sizes, int n_in,
                              void* d_out, int out_size, void* d_ws, size_t ws_size,
                              hipStream_t stream) {
    const float* h     = (const float*)d_in[0];
    const float* o     = (const float*)d_in[1];
    const float* tfidf = (const float*)d_in[2];
    const float* Wfc   = (const float*)d_in[3];
    const float* Wfc1  = (const float*)d_in[4];
    const float* Wfeat = (const float*)d_in[5];
    const float* bfeat = (const float*)d_in[6];
    const float* Wattn = (const float*)d_in[7];
    const int*   esrc  = (const int*)d_in[8];
    const int*   edst  = (const int*)d_in[9];
    float* out = (float*)d_out;

    // workspace layout (4B units):
    // zsrc[640000] zdst[2560000] escore_p[1280000] ssrc[1280000]
    // epos[1280000] cnt[40000] csr[40001] cursor[40000]  => ~28.6 MB
    float* ws      = (float*)d_ws;
    float* zsrc    = ws;
    float* zdst    = ws + 640000;
    float* escorep = ws + 3200000;
    int*   ssrc    = (int*)(ws + 4480000);
    int*   epos    = (int*)(ws + 5760000);
    int*   cnt     = (int*)(ws + 7040000);
    int*   csr     = (int*)(ws + 7080000);
    int*   cursor  = (int*)(ws + 7120001);

    hipMemsetAsync(cnt, 0, N_DST * sizeof(int), stream);

    k_zsrc<<<256, 256, 0, stream>>>(h, Wfc, zsrc);
    k_zdst<<<512, 256, O_DIM * D * sizeof(float), stream>>>(o, Wfc1, zdst);
    k_hist<<<NE / 256, 256, 0, stream>>>(edst, cnt);
    k_scan<<<1, 256, 0, stream>>>(cnt, csr, cursor);
    k_bucket<<<NE / 256, 256, 0, stream>>>(esrc, edst, cursor, ssrc, epos);
    k_edge<<<2048, 256, 0, stream>>>(tfidf, esrc, edst, epos, zsrc, zdst,
                                     Wfeat, bfeat, Wattn, escorep);
    k_post<<<N_DST / 4, 256, 0, stream>>>(csr, ssrc, escorep, zsrc, out);
}

// Round 3
// 954.215 us; speedup vs baseline: 1.1493x; 1.0739x over previous
//
#include <hip/hip_runtime.h>
#include <hip/hip_bf16.h>

#define N_SRC 10000
#define N_DST 40000
#define NE    1280000
#define IN_DIM 128
#define O_DIM  300
#define D      64
#define FEAT   64
#define NB     157   // ceil(N_DST/256)

typedef __bf16 bf16x8 __attribute__((ext_vector_type(8)));
typedef __bf16 bf16x4 __attribute__((ext_vector_type(4)));
typedef float  f32x4  __attribute__((ext_vector_type(4)));

// ---------------- K1: z_src = h @ W_fc  [10000x128]@[128x64] ----------------
// writes fp32 (for k_post) + bf16 shadow (for k_edge gathers)
__global__ __launch_bounds__(256) void k_zsrc(const float* __restrict__ h,
                                              const float* __restrict__ Wfc,
                                              float* __restrict__ z,
                                              __bf16* __restrict__ zh){
    __shared__ float w[IN_DIM * D]; // 32 KB
    for (int i = threadIdx.x; i < IN_DIM * D; i += blockDim.x) w[i] = Wfc[i];
    __syncthreads();
    int lane = threadIdx.x & 63;
    int wid  = blockIdx.x * 4 + (threadIdx.x >> 6);
    int nw   = gridDim.x * 4;
    for (int row = wid; row < N_SRC; row += nw){
        const f32x4* hp = (const f32x4*)(h + (size_t)row * IN_DIM);
        float acc = 0.f;
        #pragma unroll 4
        for (int k4 = 0; k4 < IN_DIM / 4; ++k4){
            f32x4 hv = hp[k4];
            int k = k4 * 4;
            acc += hv[0] * w[(k + 0) * D + lane];
            acc += hv[1] * w[(k + 1) * D + lane];
            acc += hv[2] * w[(k + 2) * D + lane];
            acc += hv[3] * w[(k + 3) * D + lane];
        }
        z[(size_t)row * D + lane]  = acc;
        zh[(size_t)row * D + lane] = (__bf16)acc;
    }
}

// ---------------- K2: z_dst = o @ W_fc1  [40000x300]@[300x64] ---------------
__global__ __launch_bounds__(256) void k_zdst(const float* __restrict__ o,
                                              const float* __restrict__ Wfc1,
                                              float* __restrict__ z){
    extern __shared__ float w[]; // 300*64*4 = 76.8 KB
    for (int i = threadIdx.x; i < O_DIM * D; i += blockDim.x) w[i] = Wfc1[i];
    __syncthreads();
    int lane = threadIdx.x & 63;
    int wid  = blockIdx.x * 4 + (threadIdx.x >> 6);
    int nw   = gridDim.x * 4;
    for (int row = wid; row < N_DST; row += nw){
        const f32x4* op = (const f32x4*)(o + (size_t)row * O_DIM);
        float acc = 0.f;
        #pragma unroll 5
        for (int k4 = 0; k4 < O_DIM / 4; ++k4){
            f32x4 ov = op[k4];
            int k = k4 * 4;
            acc += ov[0] * w[(k + 0) * D + lane];
            acc += ov[1] * w[(k + 1) * D + lane];
            acc += ov[2] * w[(k + 2) * D + lane];
            acc += ov[3] * w[(k + 3) * D + lane];
        }
        z[(size_t)row * D + lane] = acc;
    }
}

// ---------------- CSR build: histogram -> 3-phase scan -> bucket ------------
__global__ __launch_bounds__(256) void k_hist(const int* __restrict__ edst,
                                              int* __restrict__ cnt){
    int i = blockIdx.x * blockDim.x + threadIdx.x;
    if (i < NE) atomicAdd(&cnt[edst[i]], 1);
}

__device__ __forceinline__ int block_incl_scan(int c, int* wsum){
    int lane = threadIdx.x & 63, w = threadIdx.x >> 6;
    int v = c;
    #pragma unroll
    for (int off = 1; off < 64; off <<= 1){
        int u = __shfl_up(v, off);
        if (lane >= off) v += u;
    }
    if (lane == 63) wsum[w] = v;
    __syncthreads();
    int add = 0;
    for (int ww = 0; ww < w; ++ww) add += wsum[ww];
    return v + add;
}

// phase 1: per-block totals
__global__ __launch_bounds__(256) void k_scan1(const int* __restrict__ cnt,
                                               int* __restrict__ bsum){
    __shared__ int wsum[4];
    int i = blockIdx.x * 256 + threadIdx.x;
    int c = (i < N_DST) ? cnt[i] : 0;
    int lane = threadIdx.x & 63, w = threadIdx.x >> 6;
    int v = c;
    #pragma unroll
    for (int off = 1; off < 64; off <<= 1) v += __shfl_xor(v, off);
    if (lane == 0) wsum[w] = v;
    __syncthreads();
    if (threadIdx.x == 0)
        bsum[blockIdx.x] = wsum[0] + wsum[1] + wsum[2] + wsum[3];
}

// phase 2: exclusive scan of the 157 block totals (in place, single block)
__global__ __launch_bounds__(256) void k_scan2(int* __restrict__ bsum){
    __shared__ int wsum[4];
    int i = threadIdx.x;
    int c = (i < NB) ? bsum[i] : 0;
    int v = block_incl_scan(c, wsum);
    if (i < NB) bsum[i] = v - c;   // exclusive
}

// phase 3: full prefix -> csr & cursor
__global__ __launch_bounds__(256) void k_scan3(const int* __restrict__ cnt,
                                               const int* __restrict__ bsum,
                                               int* __restrict__ csr,
                                               int* __restrict__ cursor){
    __shared__ int wsum[4];
    int i = blockIdx.x * 256 + threadIdx.x;
    int c = (i < N_DST) ? cnt[i] : 0;
    int v = block_incl_scan(c, wsum);
    int val = bsum[blockIdx.x] + v - c;  // exclusive prefix
    if (i < N_DST){ csr[i] = val; cursor[i] = val; }
    if (blockIdx.x == 0 && threadIdx.x == 0) csr[N_DST] = NE;
}

// bucket: pos = cursor[dst]++; record src, dst, original edge id per position
__global__ __launch_bounds__(256) void k_bucket(const int* __restrict__ esrc,
                                                const int* __restrict__ edst,
                                                int* __restrict__ cursor,
                                                int* __restrict__ ssrc,
                                                int* __restrict__ sdst,
                                                int* __restrict__ sedge){
    int e = blockIdx.x * blockDim.x + threadIdx.x;
    if (e >= NE) return;
    int d = edst[e];
    int pos = atomicAdd(&cursor[d], 1);
    ssrc[pos]  = esrc[e];
    sdst[pos]  = d;
    sedge[pos] = e;
}

// ---------------- K3: per-edge attention score, CSR (dst-sorted) order ------
// One wave per 16 positions. MFMA 16x16x32_bf16, C = W_feat^T x tfidf^T.
// C/D layout: col(pos)=lane&15, row(dim)=mt*16 + (lane>>4)*4 + reg.
// Consecutive positions share dst -> zdst row loads hit L1/L2 (no 327MB refetch);
// zsrc gathers use the 1.28MB bf16 shadow (L2-resident under the tfidf stream).
__global__ __launch_bounds__(256) void k_edge(
        const float* __restrict__ tfidf,
        const int*   __restrict__ ssrc, const int* __restrict__ sdst,
        const int*   __restrict__ sedge,
        const __bf16* __restrict__ zsrch, const float* __restrict__ zdst,
        const float* __restrict__ Wfeat, const float* __restrict__ bfeat,
        const float* __restrict__ Wattn,
        float* __restrict__ escore_p){
    int lane = threadIdx.x & 63;
    int lo = lane & 15, g = lane >> 4;

    // A-frags: A[m=dim][k] = W_feat[k][dim]; lane holds m=mt*16+lo, k=kh*32+g*8+j
    bf16x8 afr[4][2];
    #pragma unroll
    for (int mt = 0; mt < 4; ++mt){
        int m = mt * 16 + lo;
        #pragma unroll
        for (int kh = 0; kh < 2; ++kh){
            #pragma unroll
            for (int j = 0; j < 8; ++j){
                int k = kh * 32 + g * 8 + j;
                afr[mt][kh][j] = (__bf16)Wfeat[k * D + m];
            }
        }
    }
    f32x4 bf4[4], wa4[4];
    #pragma unroll
    for (int mt = 0; mt < 4; ++mt){
        int db = mt * 16 + g * 4;
        bf4[mt] = *(const f32x4*)(bfeat + db);
        wa4[mt] = *(const f32x4*)(Wattn + db);
    }

    int wid = blockIdx.x * 4 + (threadIdx.x >> 6);
    int nw  = gridDim.x * 4;
    for (int tile = wid; tile < NE / 16; tile += nw){
        int p  = tile * 16 + lo;
        int se = sedge[p], ss = ssrc[p], sd = sdst[p];

        // B-frags: B[k][n=pos]=tfidf[sedge[pos]][k]; lane n=lo, k=kh*32+g*8+j
        const float* trow = tfidf + (size_t)se * FEAT;
        bf16x8 bfr[2];
        #pragma unroll
        for (int kh = 0; kh < 2; ++kh){
            f32x4 fa = *(const f32x4*)(trow + kh * 32 + g * 8);
            f32x4 fb = *(const f32x4*)(trow + kh * 32 + g * 8 + 4);
            #pragma unroll
            for (int j = 0; j < 4; ++j){
                bfr[kh][j]     = (__bf16)fa[j];
                bfr[kh][4 + j] = (__bf16)fb[j];
            }
        }

        float pacc = 0.f;
        #pragma unroll
        for (int mt = 0; mt < 4; ++mt){
            f32x4 acc = {0.f, 0.f, 0.f, 0.f};
            acc = __builtin_amdgcn_mfma_f32_16x16x32_bf16(afr[mt][0], bfr[0], acc, 0, 0, 0);
            acc = __builtin_amdgcn_mfma_f32_16x16x32_bf16(afr[mt][1], bfr[1], acc, 0, 0, 0);
            int db = mt * 16 + g * 4;
            bf16x4 zs = *(const bf16x4*)(zsrch + (size_t)ss * D + db);
            f32x4  zd = *(const f32x4*)(zdst + (size_t)sd * D + db);
            #pragma unroll
            for (int r = 0; r < 4; ++r){
                float z2 = acc[r] + (float)zs[r] + zd[r] + bf4[mt][r];
                float z3 = z2 > 0.f ? z2 : 0.01f * z2;   // leaky_relu(0.01)
                pacc += z3 * wa4[mt][r];
            }
        }
        pacc += __shfl_xor(pacc, 16);
        pacc += __shfl_xor(pacc, 32);
        if (lane < 16)
            escore_p[tile * 16 + lane] = pacc;   // coalesced, already CSR order
    }
}

// ---------------- K4: fused segment softmax + weighted gather ---------------
// One wave per dst node. lane = dim in the accumulation phase.
__global__ __launch_bounds__(256) void k_post(const int* __restrict__ csr,
                                              const int* __restrict__ ssrc,
                                              const float* __restrict__ escore_p,
                                              const float* __restrict__ zsrc,
                                              float* __restrict__ out){
    int lane = threadIdx.x & 63;
    int d    = blockIdx.x * 4 + (threadIdx.x >> 6);
    if (d >= N_DST) return;
    int beg = csr[d], end = csr[d + 1];

    // pass A: segment max
    float m = -3.4e38f;
    for (int j = beg + lane; j < end; j += 64)
        m = fmaxf(m, escore_p[j]);
    #pragma unroll
    for (int off = 1; off < 64; off <<= 1)
        m = fmaxf(m, __shfl_xor(m, off));

    // pass B: exp-sum
    float ssum = 0.f;
    for (int j = beg + lane; j < end; j += 64)
        ssum += __expf(escore_p[j] - m);
    #pragma unroll
    for (int off = 1; off < 64; off <<= 1)
        ssum += __shfl_xor(ssum, off);
    float inv = 1.f / fmaxf(ssum, 1e-9f);

    // pass C: out[d][lane] = sum_e alpha_e * zsrc[src_e][lane]
    float acc = 0.f;
    for (int base = beg; base < end; base += 64){
        int n = end - base; if (n > 64) n = 64;
        int   sj = 0;
        float aj = 0.f;
        if (base + lane < end){
            sj = ssrc[base + lane];
            aj = __expf(escore_p[base + lane] - m) * inv;
        }
        for (int t = 0; t < n; ++t){
            int   s = __shfl(sj, t);
            float a = __shfl(aj, t);
            acc += a * zsrc[(size_t)s * D + lane];
        }
    }
    out[(size_t)d * D + lane] = acc;
}

extern "C" void kernel_launch(void* const* d_in, const int* in_sizes, int n_in,
                              void* d_out, int out_size, void* d_ws, size_t ws_size,
                              hipStream_t stream) {
    const float* h     = (const float*)d_in[0];
    const float* o     = (const float*)d_in[1];
    const float* tfidf = (const float*)d_in[2];
    const float* Wfc   = (const float*)d_in[3];
    const float* Wfc1  = (const float*)d_in[4];
    const float* Wfeat = (const float*)d_in[5];
    const float* bfeat = (const float*)d_in[6];
    const float* Wattn = (const float*)d_in[7];
    const int*   esrc  = (const int*)d_in[8];
    const int*   edst  = (const int*)d_in[9];
    float* out = (float*)d_out;

    // workspace layout (4B units), ~35 MB total
    float*  ws      = (float*)d_ws;
    float*  zsrc    = ws;                                  // 640000
    float*  zdst    = ws + 640000;                         // 2560000
    __bf16* zsrch   = (__bf16*)(ws + 3200000);             // 320000 (bf16 x 640000)
    float*  escorep = ws + 3520000;                        // 1280000
    int*    ssrc    = (int*)(ws + 4800000);                // 1280000
    int*    sdst    = (int*)(ws + 6080000);                // 1280000
    int*    sedge   = (int*)(ws + 7360000);                // 1280000
    int*    cnt     = (int*)(ws + 8640000);                // 40000
    int*    csr     = (int*)(ws + 8680000);                // 40001
    int*    cursor  = (int*)(ws + 8720002);                // 40000
    int*    bsum    = (int*)(ws + 8760002);                // NB

    hipMemsetAsync(cnt, 0, N_DST * sizeof(int), stream);

    k_zsrc<<<256, 256, 0, stream>>>(h, Wfc, zsrc, zsrch);
    k_zdst<<<512, 256, O_DIM * D * sizeof(float), stream>>>(o, Wfc1, zdst);
    k_hist<<<NE / 256, 256, 0, stream>>>(edst, cnt);
    k_scan1<<<NB, 256, 0, stream>>>(cnt, bsum);
    k_scan2<<<1, 256, 0, stream>>>(bsum);
    k_scan3<<<NB, 256, 0, stream>>>(cnt, bsum, csr, cursor);
    k_bucket<<<NE / 256, 256, 0, stream>>>(esrc, edst, cursor, ssrc, sdst, sedge);
    k_edge<<<4096, 256, 0, stream>>>(tfidf, ssrc, sdst, sedge, zsrch, zdst,
                                     Wfeat, bfeat, Wattn, escorep);
    k_post<<<N_DST / 4, 256, 0, stream>>>(csr, ssrc, escorep, zsrc, out);
}